// Round 13
// baseline (265.445 us; speedup 1.0000x reference)
//
#include <hip/hip_runtime.h>
#include <hip/hip_cooperative_groups.h>
#include <math.h>

namespace cg = cooperative_groups;

#define NM    4096          // output modes
#define HALFN 2048
#define MR    8192          // oversampled grid (2x)
#define MRM   (MR - 1)
#define TPB   512
#define NBLK  256
#define W     6             // Gaussian taps (E = 6.66)
#define FSCALE 65536.0f
#define INVFS  (1.0f / 65536.0f)

// hw trig/exp: v_sin/v_cos take REVOLUTIONS; v_exp_f32 computes 2^x.
__device__ __forceinline__ float sin2pi(float r) {
    float o; asm volatile("v_sin_f32 %0, %1" : "=v"(o) : "v"(r)); return o;
}
__device__ __forceinline__ float cos2pi(float r) {
    float o; asm volatile("v_cos_f32 %0, %1" : "=v"(o) : "v"(r)); return o;
}
__device__ __forceinline__ float exp2a(float x) {
    float o; asm volatile("v_exp_f32 %0, %1" : "=v"(o) : "v"(x)); return o;
}

// Single cooperative kernel: spread -> reduce -> 4-step FFT -> deconv.
// ws (ints): [0,16384) = final grid G (re|im planar);
//            [16384 + b*16384 ...) = block b's partial grid.
// After reduce, floats at ws+16384 are reused for the FFT intermediate Y.
__global__ __launch_bounds__(TPB) void nufft_all(
    const float* __restrict__ pts, const float* __restrict__ vre,
    const float* __restrict__ vim, float* __restrict__ ws,
    float* __restrict__ out, int M, int ppb, int out_size,
    float nalpha, float4 cA, float2 cB, float sfac, float taul2e)
{
    __shared__ __align__(16) int smem[2 * MR];   // 64 KB
    int* gre = smem;
    int* gim = smem + MR;
    const int tid = threadIdx.x;
    const int b   = blockIdx.x;
    cg::grid_group grid = cg::this_grid();

    // ================= phase 1: spread into private LDS int grid ============
    {
        const float C[W] = {cA.x, cA.y, cA.z, cA.w, cB.x, cB.y};
        for (int i = tid; i < 2 * MR; i += TPB) smem[i] = 0;
        __syncthreads();

        const int j0   = b * ppb;
        const int jend = min(j0 + ppb, M);
        const float inv2pi = 0.15915494309189535f;

        for (int j = j0 + tid; j < jend; j += TPB) {
            float x  = pts[j];
            float cr = vre[j];
            float ci = vim[j];
            float u = x * inv2pi;
            u -= floorf(u);                 // [0,1)
            float p  = u * (float)MR;
            float fl = floorf(p);
            int   i0 = (int)fl - 2;
            float t0 = (fl - p) - 2.0f;     // (-3, -2]
            float E1 = exp2a(nalpha * t0 * t0);
            float r  = exp2a(2.0f * nalpha * t0);
            float crs = cr * FSCALE * E1;
            float cis = ci * FSCALE * E1;
            float w = 1.0f;
#pragma unroll
            for (int i = 0; i < W; ++i) {
                float wgt = w * C[i];
                int m = (i0 + i) & MRM;
                atomicAdd(&gre[m], (int)(wgt * crs));   // native ds_add_u32
                atomicAdd(&gim[m], (int)(wgt * cis));
                w *= r;
            }
        }
        __syncthreads();

        // coalesced int4 partial writeback
        int4* buf = (int4*)((int*)ws + 16384 + (size_t)b * 16384);
        const int4* s4 = (const int4*)smem;
        for (int i = tid; i < MR / 2; i += TPB) buf[i] = s4[i];
    }
    __threadfence();
    grid.sync();

    // ================= phase 2: reduce partials -> G (no atomics) ===========
    {
        int cc = tid & 15;                 // column-in-block
        int r  = tid >> 4;                 // partial-group [0,32)
        int c4 = b * 16 + cc;              // int4 column [0,4096)
        const int4* P = (const int4*)ws + 4096;   // partials base (int4 units)
        int4 s = make_int4(0, 0, 0, 0);
#pragma unroll
        for (int q = 0; q < 8; ++q) {
            int4 v = P[(size_t)(r + 32 * q) * 4096 + c4];
            s.x += v.x; s.y += v.y; s.z += v.z; s.w += v.w;
        }
        int4* t4 = (int4*)smem;            // 512 int4 = 8 KB scratch
        t4[tid] = s;
        __syncthreads();
#pragma unroll
        for (int off = 16; off >= 1; off >>= 1) {
            if (r < off) {
                int4 a = t4[tid], c = t4[tid + off * 16];
                a.x += c.x; a.y += c.y; a.z += c.z; a.w += c.w;
                t4[tid] = a;
            }
            __syncthreads();
        }
        if (r == 0) ((int4*)ws)[c4] = t4[cc];
    }
    __threadfence();
    grid.sync();

    // ================= phase 3: 64 x 128-pt FFT over n1 + twiddle ===========
    // x[n] with n = n1*64 + n2; this block handles n2 = b (b < 64).
    // Y[k1][n2] = e^{+2pi i n2 k1/8192} * sum_n1 x[n1*64+n2] e^{+2pi i n1 k1/128}
    if (b < 64) {
        float* sre = (float*)smem;         // 128 floats
        float* sim = (float*)smem + 128;
        const int* Gi = (const int*)ws;
        if (tid < 128) {
            int r = __brev((unsigned)tid) >> 25;     // bitrev7
            sre[r] = (float)Gi[tid * 64 + b]      * INVFS;
            sim[r] = (float)Gi[MR + tid * 64 + b] * INVFS;
        }
        __syncthreads();
        for (int half = 1; half < 128; half <<= 1) {
            if (tid < 64) {
                int t  = tid & (half - 1);
                int i0 = ((tid ^ t) << 1) + t;
                float tf = (float)t / (float)(half << 1);
                float wr = cos2pi(tf), wi = sin2pi(tf);   // e^{+2pi i t/len}
                float xr = sre[i0 + half], xi = sim[i0 + half];
                float vr = fmaf(xr, wr, -(xi * wi));
                float vi = fmaf(xr, wi,   xi * wr);
                float ur = sre[i0], ui = sim[i0];
                sre[i0] = ur + vr;         sim[i0] = ui + vi;
                sre[i0 + half] = ur - vr;  sim[i0 + half] = ui - vi;
            }
            __syncthreads();
        }
        if (tid < 128) {
            int k1 = tid;
            float tf = (float)(k1 * b) * (1.0f / 8192.0f);
            float wr = cos2pi(tf), wi = sin2pi(tf);
            float ar = sre[k1], ai = sim[k1];
            float yr = fmaf(ar, wr, -(ai * wi));
            float yi = fmaf(ar, wi,   ai * wr);
            float* Y = ws + 16384;
            Y[k1 * 64 + b]      = yr;
            Y[MR + k1 * 64 + b] = yi;
        }
    }
    __threadfence();
    grid.sync();

    // ================= phase 4: 128 x 64-pt FFT over n2 + deconv + out ======
    // X[k2*128+k1] = sum_n2 Y[k1][n2] e^{+2pi i n2 k2/64}; this block: k1 = b.
    if (b < 128) {
        float* sre = (float*)smem;         // 64 floats
        float* sim = (float*)smem + 64;
        const float* Y = ws + 16384;
        if (tid < 64) {
            int r = __brev((unsigned)tid) >> 26;     // bitrev6
            sre[r] = Y[b * 64 + tid];
            sim[r] = Y[MR + b * 64 + tid];
        }
        __syncthreads();
        for (int half = 1; half < 64; half <<= 1) {
            if (tid < 32) {
                int t  = tid & (half - 1);
                int i0 = ((tid ^ t) << 1) + t;
                float tf = (float)t / (float)(half << 1);
                float wr = cos2pi(tf), wi = sin2pi(tf);
                float xr = sre[i0 + half], xi = sim[i0 + half];
                float vr = fmaf(xr, wr, -(xi * wi));
                float vi = fmaf(xr, wi,   xi * wr);
                float ur = sre[i0], ui = sim[i0];
                sre[i0] = ur + vr;         sim[i0] = ui + vi;
                sre[i0 + half] = ur - vr;  sim[i0 + half] = ui - vi;
            }
            __syncthreads();
        }
        if (tid < 64) {
            int k2 = tid;
            bool lo = (k2 < 16), hi = (k2 >= 48);
            if (lo || hi) {
                int k8  = k2 * 128 + b;
                int k   = lo ? k8 : k8 - 8192;       // signed mode
                int idx = lo ? k8 : k8 - 4096;       // FFT-order output index
                float kk = (float)k;
                float corr = sfac * exp2a(kk * kk * taul2e);
                float fre = sre[k2] * corr;
                float fim = sim[k2] * corr;
                if (out_size >= 2 * NM) {
                    out[idx]      = fre;
                    out[NM + idx] = fim;
                } else {
                    out[idx] = fre;
                }
            }
        }
    }
}

extern "C" void kernel_launch(void* const* d_in, const int* in_sizes, int n_in,
                              void* d_out, int out_size, void* d_ws, size_t ws_size,
                              hipStream_t stream)
{
    const float* pts = (const float*)d_in[0];
    const float* vre = (const float*)d_in[1];
    const float* vim = (const float*)d_in[2];
    float* out = (float*)d_out;
    float* ws  = (float*)d_ws;
    int M = in_sizes[0];

    // Gaussian kernel, w=6, balanced: alpha = gam*sqrt(dif)/6, E = 6.66
    const double PI  = 3.14159265358979323846;
    const double gam = 2.0 * PI / (double)MR;
    const double dif = (double)(MR - HALFN) * (MR - HALFN) - (double)HALFN * HALFN;
    const double alpha = gam * sqrt(dif) / 6.0;
    const double tau = gam * gam / (4.0 * alpha);
    const double L2E = 1.4426950408889634;
    float nalpha = (float)(-alpha * L2E);
    float sfac   = (float)sqrt(alpha / PI);
    float taul2e = (float)(tau * L2E);
    float4 cA = make_float4(1.0f, (float)exp(-alpha), (float)exp(-alpha * 4.0),
                            (float)exp(-alpha * 9.0));
    float2 cB = make_float2((float)exp(-alpha * 16.0), (float)exp(-alpha * 25.0));

    int ppb = (M + NBLK - 1) / NBLK;
    int osz = out_size;

    void* args[] = { (void*)&pts, (void*)&vre, (void*)&vim, (void*)&ws,
                     (void*)&out, (void*)&M, (void*)&ppb, (void*)&osz,
                     (void*)&nalpha, (void*)&cA, (void*)&cB,
                     (void*)&sfac, (void*)&taul2e };
    hipLaunchCooperativeKernel((void*)nufft_all, dim3(NBLK), dim3(TPB),
                               args, 0, stream);
}

// Round 14
// 29.356 us; speedup vs baseline: 9.0423x; 9.0423x over previous
//
#include <hip/hip_runtime.h>
#include <math.h>

#define NM    4096          // output modes
#define HALFN 2048
#define MR    8192          // oversampled grid (2x)
#define MRM   (MR - 1)
#define STPB  512           // spread threads per block
#define NB    256           // partial grids
#define W     6             // Gaussian taps (E = 6.66, err ~1.3e-3 rel)
#define FSCALE 65536.0f     // fixed-point scale 2^16
#define INVFS  (1.0f / 65536.0f)

// hw trig/exp: v_sin/v_cos take REVOLUTIONS; v_exp_f32 computes 2^x.
__device__ __forceinline__ float sin2pi(float r) {
    float o; asm volatile("v_sin_f32 %0, %1" : "=v"(o) : "v"(r)); return o;
}
__device__ __forceinline__ float cos2pi(float r) {
    float o; asm volatile("v_cos_f32 %0, %1" : "=v"(o) : "v"(r)); return o;
}
__device__ __forceinline__ float exp2a(float x) {
    float o; asm volatile("v_exp_f32 %0, %1" : "=v"(o) : "v"(x)); return o;
}

// ---------------- 1) spread: points -> privatized LDS int grid -> int partials
// ws (ints): [0,16384) = final grid G (re|im planar);
//            [16384 + b*16384 ...) = block b partial grid;
// floats at ws+16384 are reused as FFT intermediate Y after the reduce.
__global__ __launch_bounds__(STPB) void nufft_spread(
    const float* __restrict__ pts, const float* __restrict__ vre,
    const float* __restrict__ vim, float* __restrict__ ws,
    int M, int ppb, float nalpha, float4 cA, float2 cB)
{
    __shared__ int gre[MR];
    __shared__ int gim[MR];
    const int tid = threadIdx.x;
    const int b   = blockIdx.x;
    const float C[W] = {cA.x, cA.y, cA.z, cA.w, cB.x, cB.y};

    for (int i = tid; i < MR; i += STPB) { gre[i] = 0; gim[i] = 0; }
    __syncthreads();

    const int j0   = b * ppb;
    const int jend = min(j0 + ppb, M);
    const float inv2pi = 0.15915494309189535f;

    for (int j = j0 + tid; j < jend; j += STPB) {
        float x  = pts[j];
        float cr = vre[j];
        float ci = vim[j];
        float u = x * inv2pi;
        u -= floorf(u);                 // [0,1)
        float p  = u * (float)MR;       // grid position [0, 8192]
        float fl = floorf(p);
        int   i0 = (int)fl - 2;
        float t0 = (fl - p) - 2.0f;     // m - p for m = i0, in (-3, -2]
        float E1 = exp2a(nalpha * t0 * t0);      // exp(-alpha*t0^2)
        float r  = exp2a(2.0f * nalpha * t0);    // exp(-2*alpha*t0)
        float crs = cr * FSCALE * E1;
        float cis = ci * FSCALE * E1;
        float w = 1.0f;
#pragma unroll
        for (int i = 0; i < W; ++i) {
            float wgt = w * C[i];
            int m = (i0 + i) & MRM;
            atomicAdd(&gre[m], (int)(wgt * crs));   // native ds_add_u32
            atomicAdd(&gim[m], (int)(wgt * cis));
            w *= r;
        }
    }
    __syncthreads();

    // raw int writeback, vectorized
    int4* buf = (int4*)((int*)ws + 16384 + (size_t)b * 16384);
    const int4* g4r = (const int4*)gre;
    const int4* g4i = (const int4*)gim;
    for (int i = tid; i < MR / 4; i += STPB) {
        buf[i]          = g4r[i];
        buf[MR / 4 + i] = g4i[i];
    }
}

// ---------------- 2) reduce int partials -> int grid G ----------------------
// 16384 threads, one int column each, coalesced; unroll 32 => 2 MB in flight.
__global__ __launch_bounds__(64) void nufft_reduce_grid(
    float* __restrict__ ws, int nb)
{
    int i = blockIdx.x * 64 + threadIdx.x;           // [0, 16384)
    const int* src = (const int*)ws + 16384 + i;
    int s = 0;
#pragma unroll 32
    for (int b = 0; b < nb; ++b) s += src[(size_t)b * 16384];
    ((int*)ws)[i] = s;
}

// ---------------- 3) FFT step 1: 64 x 128-pt FFT over n1 + twiddle ----------
// x[n], n = n1*64 + n2; block b = n2. (Verified in round 13 phase 3.)
// Y[k1*64+n2] = e^{+2pi i n2 k1/8192} * sum_n1 x[n1*64+n2] e^{+2pi i n1 k1/128}
__global__ __launch_bounds__(128) void nufft_fft1(float* __restrict__ ws)
{
    __shared__ float sre[128];
    __shared__ float sim[128];
    const int tid = threadIdx.x;
    const int b   = blockIdx.x;                      // n2
    const int* Gi = (const int*)ws;

    int r = __brev((unsigned)tid) >> 25;             // bitrev7
    sre[r] = (float)Gi[tid * 64 + b]      * INVFS;
    sim[r] = (float)Gi[MR + tid * 64 + b] * INVFS;
    __syncthreads();

    for (int half = 1; half < 128; half <<= 1) {
        if (tid < 64) {
            int t  = tid & (half - 1);
            int i0 = ((tid ^ t) << 1) + t;
            float tf = (float)t / (float)(half << 1);
            float wr = cos2pi(tf), wi = sin2pi(tf);  // e^{+2pi i t/len}
            float xr = sre[i0 + half], xi = sim[i0 + half];
            float vr = fmaf(xr, wr, -(xi * wi));
            float vi = fmaf(xr, wi,   xi * wr);
            float ur = sre[i0], ui = sim[i0];
            sre[i0] = ur + vr;         sim[i0] = ui + vi;
            sre[i0 + half] = ur - vr;  sim[i0 + half] = ui - vi;
        }
        __syncthreads();
    }

    int k1 = tid;
    float tf = (float)(k1 * b) * (1.0f / 8192.0f);
    float wr = cos2pi(tf), wi = sin2pi(tf);
    float ar = sre[k1], ai = sim[k1];
    float* Y = ws + 16384;
    Y[k1 * 64 + b]      = fmaf(ar, wr, -(ai * wi));
    Y[MR + k1 * 64 + b] = fmaf(ar, wi,   ai * wr);
}

// ---------------- 4) FFT step 2: 128 x 64-pt FFT + deconv + output ----------
// X[k2*128+k1] = sum_n2 Y[k1*64+n2] e^{+2pi i n2 k2/64}; block = k1.
// (Verified in round 13 phase 4.)
__global__ __launch_bounds__(64) void nufft_fft2(
    const float* __restrict__ ws, float* __restrict__ out,
    int out_size, float sfac, float taul2e)
{
    __shared__ float sre[64];
    __shared__ float sim[64];
    const int tid = threadIdx.x;
    const int b   = blockIdx.x;                      // k1
    const float* Y = ws + 16384;

    int r = __brev((unsigned)tid) >> 26;             // bitrev6
    sre[r] = Y[b * 64 + tid];
    sim[r] = Y[MR + b * 64 + tid];
    __syncthreads();

    for (int half = 1; half < 64; half <<= 1) {
        if (tid < 32) {
            int t  = tid & (half - 1);
            int i0 = ((tid ^ t) << 1) + t;
            float tf = (float)t / (float)(half << 1);
            float wr = cos2pi(tf), wi = sin2pi(tf);
            float xr = sre[i0 + half], xi = sim[i0 + half];
            float vr = fmaf(xr, wr, -(xi * wi));
            float vi = fmaf(xr, wi,   xi * wr);
            float ur = sre[i0], ui = sim[i0];
            sre[i0] = ur + vr;         sim[i0] = ui + vi;
            sre[i0 + half] = ur - vr;  sim[i0 + half] = ui - vi;
        }
        __syncthreads();
    }

    int k2 = tid;
    bool lo = (k2 < 16), hi = (k2 >= 48);
    if (lo || hi) {
        int k8  = k2 * 128 + b;
        int k   = lo ? k8 : k8 - 8192;               // signed mode
        int idx = lo ? k8 : k8 - 4096;               // FFT-order output index
        float kk = (float)k;
        float corr = sfac * exp2a(kk * kk * taul2e);
        float fre = sre[k2] * corr;
        float fim = sim[k2] * corr;
        if (out_size >= 2 * NM) {
            out[idx]      = fre;
            out[NM + idx] = fim;
        } else {
            out[idx] = fre;
        }
    }
}

extern "C" void kernel_launch(void* const* d_in, const int* in_sizes, int n_in,
                              void* d_out, int out_size, void* d_ws, size_t ws_size,
                              hipStream_t stream)
{
    const float* pts = (const float*)d_in[0];
    const float* vre = (const float*)d_in[1];
    const float* vim = (const float*)d_in[2];
    float* out = (float*)d_out;
    float* ws  = (float*)d_ws;
    const int M = in_sizes[0];

    // Gaussian kernel, w=6, balanced: alpha = gam*sqrt(dif)/6, E = 9*alpha = 6.66
    const double PI  = 3.14159265358979323846;
    const double gam = 2.0 * PI / (double)MR;
    const double dif = (double)(MR - HALFN) * (MR - HALFN) - (double)HALFN * HALFN;
    const double alpha = gam * sqrt(dif) / 6.0;
    const double tau = gam * gam / (4.0 * alpha);
    const double L2E = 1.4426950408889634;
    const float nalpha = (float)(-alpha * L2E);                // exp2 scale
    const float sfac   = (float)sqrt(alpha / PI);
    const float taul2e = (float)(tau * L2E);
    float4 cA = make_float4(1.0f, (float)exp(-alpha), (float)exp(-alpha * 4.0),
                            (float)exp(-alpha * 9.0));
    float2 cB = make_float2((float)exp(-alpha * 16.0), (float)exp(-alpha * 25.0));

    int nb = NB;
    while (nb > 1 && (size_t)(nb + 1) * 65536 > ws_size) nb >>= 1;
    int ppb = (M + nb - 1) / nb;

    hipLaunchKernelGGL(nufft_spread, dim3(nb), dim3(STPB), 0, stream,
                       pts, vre, vim, ws, M, ppb, nalpha, cA, cB);
    hipLaunchKernelGGL(nufft_reduce_grid, dim3(256), dim3(64), 0, stream, ws, nb);
    hipLaunchKernelGGL(nufft_fft1, dim3(64), dim3(128), 0, stream, ws);
    hipLaunchKernelGGL(nufft_fft2, dim3(128), dim3(64), 0, stream,
                       ws, out, out_size, sfac, taul2e);
}